// Round 9
// baseline (1639.734 us; speedup 1.0000x reference)
//
#include <hip/hip_runtime.h>
#include <hip/hip_fp16.h>
#include <cstdint>
#include <cstddef>

#define Bn 4
#define Hn 16
#define Sn 2048
#define Dn 128

typedef _Float16 half8  __attribute__((ext_vector_type(8)));
typedef _Float16 half4v __attribute__((ext_vector_type(4)));
typedef float    f32x16 __attribute__((ext_vector_type(16)));
typedef float    f32x4v __attribute__((ext_vector_type(4)));
typedef unsigned uint4v __attribute__((ext_vector_type(4)));
typedef int      i32x2  __attribute__((ext_vector_type(2)));

#define PSTR 268   // fp32 LDS row stride

__device__ __forceinline__ int pk_f16(float a, float b){
  auto h = __builtin_amdgcn_cvt_pkrtz(a, b);   // __fp16x2
  return __builtin_bit_cast(int, h);
}

// ---------------- prep kernels ----------------

__global__ void k_rope_table(float2* __restrict__ tab){
  const int idx = blockIdx.x*256 + threadIdx.x;     // [s][i], 2048*64
  const int i = idx & 63, s = idx >> 6;
  const double invf = exp(-(double)i * (9.210340371976184 / 64.0)); // 10000^(-i/64)
  const double ang  = (double)s * invf;
  float2 cs; cs.x = (float)cos(ang); cs.y = (float)sin(ang);
  tab[idx] = cs;
}

__global__ void k_pack_qk(const float* __restrict__ q, const float* __restrict__ k,
                          const float2* __restrict__ tab,
                          half8* __restrict__ qp, half8* __restrict__ kp){
  const int t    = blockIdx.x*256 + threadIdx.x;    // 2,097,152 chunks
  const int lane = t & 63, ln = lane & 31, h = lane >> 5;
  const int dc   = (t >> 6) & 7;
  const int blk  = (t >> 9) & 63;
  const int bh   = t >> 15;
  const int s    = blk*32 + ln;
  const size_t roff = ((size_t)bh*Sn + s)*Dn + dc*16 + h*8;
  const float4 a0 = *(const float4*)(q + roff);
  const float4 a1 = *(const float4*)(q + roff + 4);
  const float4 b0 = *(const float4*)(k + roff);
  const float4 b1 = *(const float4*)(k + roff + 4);
  const float2* tb = tab + s*64 + dc*8 + h*4;
  const float2 c0 = tb[0], c1 = tb[1], c2 = tb[2], c3 = tb[3];
  const float SC = 0.08838834764831845f;            // 1/sqrt(128) folded into q
  half8 qo, ko;
  qo[0] = (_Float16)((a0.x*c0.x - a0.y*c0.y)*SC);
  qo[1] = (_Float16)((a0.y*c0.x + a0.x*c0.y)*SC);
  qo[2] = (_Float16)((a0.z*c1.x - a0.w*c1.y)*SC);
  qo[3] = (_Float16)((a0.w*c1.x + a0.z*c1.y)*SC);
  qo[4] = (_Float16)((a1.x*c2.x - a1.y*c2.y)*SC);
  qo[5] = (_Float16)((a1.y*c2.x + a1.x*c2.y)*SC);
  qo[6] = (_Float16)((a1.z*c3.x - a1.w*c3.y)*SC);
  qo[7] = (_Float16)((a1.w*c3.x + a1.z*c3.y)*SC);
  ko[0] = (_Float16)(b0.x*c0.x - b0.y*c0.y);
  ko[1] = (_Float16)(b0.y*c0.x + b0.x*c0.y);
  ko[2] = (_Float16)(b0.z*c1.x - b0.w*c1.y);
  ko[3] = (_Float16)(b0.w*c1.x + b0.z*c1.y);
  ko[4] = (_Float16)(b1.x*c2.x - b1.y*c2.y);
  ko[5] = (_Float16)(b1.y*c2.x + b1.x*c2.y);
  ko[6] = (_Float16)(b1.z*c3.x - b1.w*c3.y);
  ko[7] = (_Float16)(b1.w*c3.x + b1.z*c3.y);
  qp[t] = qo;
  kp[t] = ko;
}

__global__ void k_pack_v(const float* __restrict__ v, half8* __restrict__ vp){
  const int t    = blockIdx.x*256 + threadIdx.x;    // 2,097,152 chunks
  const int lane = t & 63, ln = lane & 31, h = lane >> 5;
  const int dt   = (t >> 6) & 3;
  const int k16  = (t >> 8) & 127;
  const int bh   = t >> 15;
  const size_t base = ((size_t)bh*Sn + k16*16 + h*8)*Dn + dt*32 + ln;
  half8 o;
#pragma unroll
  for (int j = 0; j < 8; ++j) o[j] = (_Float16)v[base + (size_t)j*Dn];
  vp[t] = o;
}

__global__ void k_maskbits(const int* __restrict__ mask, unsigned* __restrict__ mtb){
  const int g = blockIdx.x*256 + threadIdx.x;       // [q32][k], 64*2048
  const int k = g & (Sn-1), q32 = g >> 11;
  unsigned bits = 0u;
  for (int j = 0; j < 32; ++j)
    bits |= (mask[(size_t)(q32*32 + j)*Sn + k] != 0 ? 1u : 0u) << j;
  mtb[g] = bits;
}

// ---------------- pass A: per-row softmax stats (m, L) ----------------

__global__ __launch_bounds__(512, 3) void attn_stats(
    const half8* __restrict__ qp, const half8* __restrict__ kp,
    const unsigned* __restrict__ mtb, float2* __restrict__ mL)
{
  const int bid  = blockIdx.x;
  const int work = ((bid & 7) << 6) + (bid >> 3);   // XCD-contiguous bh ranges
  const int bh   = work >> 3;
  const int qg   = work & 7;
  const int w    = threadIdx.x >> 6;
  const int l    = threadIdx.x & 63;
  const int ln   = l & 31;
  const int h    = l >> 5;
  const int qb   = qg*8 + w;

  half8 qf[8];
#pragma unroll
  for (int dc = 0; dc < 8; ++dc)
    qf[dc] = qp[(((size_t)bh*64 + qb)*8 + dc)*64 + l];

  const unsigned* mrow = mtb + (size_t)qb*Sn;
  float m = -3.0e38f, L = 0.f;

  for (int kt = 0; kt < 64; ++kt){
    const half8* kf = kp + (((size_t)bh*64 + kt)*8)*64 + l;
    f32x16 a;
#pragma unroll
    for (int i = 0; i < 16; ++i) a[i] = 0.f;
#pragma unroll
    for (int dc = 0; dc < 8; ++dc)
      a = __builtin_amdgcn_mfma_f32_32x32x16_f16(kf[(size_t)dc*64], qf[dc], a, 0, 0, 0);

    float mt = -3.0e38f;
#pragma unroll
    for (int mm = 0; mm < 4; ++mm){
      const uint4v dw = *(const uint4v*)(mrow + kt*32 + mm*8 + h*4);
#pragma unroll
      for (int aa = 0; aa < 4; ++aa){
        const int r = mm*4 + aa;
        float s = ((dw[aa] >> ln) & 1u) ? a[r] : -1.0e30f;
        a[r] = s;
        mt = fmaxf(mt, s);
      }
    }
    const float mn = fmaxf(m, mt);
    L *= __expf(m - mn);
#pragma unroll
    for (int r = 0; r < 16; ++r) L += __expf(a[r] - mn);
    m = mn;
  }

  const float mo = __shfl_xor(m, 32, 64);
  const float Lo = __shfl_xor(L, 32, 64);
  const float mn = fmaxf(m, mo);
  const float Lc = L*__expf(m - mn) + Lo*__expf(mo - mn);
  if (l < 32){
    float2 st; st.x = mn; st.y = Lc;
    mL[(size_t)bh*Sn + qb*32 + ln] = st;
  }
}

// ---------------- pass B: compute + PV; p -> ws as fp16 (full, unchunked) ----------------
// grid 4096 = BH*64 strips; block 512 = 8 waves, one 32-row q strip.
// p stored fp16 to ws (row-contiguous 512B runs, plain cached stores so L3
// can serve k_expand). out stored fp32 direct.

__global__ __launch_bounds__(512, 2) void attn_pv(
    const half8* __restrict__ qp, const half8* __restrict__ kp,
    const half8* __restrict__ vp, const unsigned* __restrict__ mtb,
    const float2* __restrict__ mL,
    float* __restrict__ out, _Float16* __restrict__ wsp)
{
  __shared__ float ps[32][PSTR];     // 34.3 KB
  __shared__ float lds_out[128*33];  // 16.9 KB

  const int bid   = blockIdx.x;
  const int work  = ((bid & 7) << 9) + (bid >> 3);  // XCD-contiguous bh ranges
  const int bh    = work >> 6;
  const int qb    = work & 63;
  const int tid   = threadIdx.x;
  const int w     = tid >> 6;
  const int l     = tid & 63;
  const int ln    = l & 31;
  const int h     = l >> 5;

  for (int i = tid; i < 128*33; i += 512) lds_out[i] = 0.f;

  half8 qf[8];
#pragma unroll
  for (int dc = 0; dc < 8; ++dc)
    qf[dc] = qp[(((size_t)bh*64 + qb)*8 + dc)*64 + l];

  const float2 st = mL[(size_t)bh*Sn + qb*32 + ln];
  const float m    = st.x;
  const float rinv = 1.0f / st.y;

  f32x16 oacc[4];
#pragma unroll
  for (int dt = 0; dt < 4; ++dt)
#pragma unroll
    for (int i = 0; i < 16; ++i) oacc[dt][i] = 0.f;

  const unsigned* mrow = mtb + (size_t)qb*Sn;
  _Float16* pws = wsp + (size_t)work*32*Sn;   // fp16 strip, 128 KB

  for (int g = 0; g < 8; ++g){
    const int kt = g*8 + w;

    // QK^T tile (bitwise-identical MFMA sequence to pass A)
    const half8* kf = kp + (((size_t)bh*64 + kt)*8)*64 + l;
    f32x16 a;
#pragma unroll
    for (int i = 0; i < 16; ++i) a[i] = 0.f;
#pragma unroll
    for (int dc = 0; dc < 8; ++dc)
      a = __builtin_amdgcn_mfma_f32_32x32x16_f16(kf[(size_t)dc*64], qf[dc], a, 0, 0, 0);

    // mask + p = exp(s-m)/L -> ps[q=ln][w*32 + col]
#pragma unroll
    for (int mm = 0; mm < 4; ++mm){
      const uint4v dw = *(const uint4v*)(mrow + kt*32 + mm*8 + h*4);
#pragma unroll
      for (int aa = 0; aa < 4; ++aa){
        const int r = mm*4 + aa;
        const float s = ((dw[aa] >> ln) & 1u) ? a[r] : -1.0e30f;
        a[r] = __expf(s - m) * rinv;
      }
    }
#pragma unroll
    for (int gg = 0; gg < 4; ++gg){
      const int c = w*32 + gg*8 + h*4;
      float2 e0, e1;
      e0.x = a[4*gg+0]; e0.y = a[4*gg+1];
      e1.x = a[4*gg+2]; e1.y = a[4*gg+3];
      *(float2*)&ps[ln][c]   = e0;
      *(float2*)&ps[ln][c+2] = e1;
    }
    __syncthreads();

    // p store: fp16, wave w stores rows w*4..w*4+3, 512B contiguous per row
#pragma unroll
    for (int i = 0; i < 4; ++i){
      const int row = w*4 + i;
      const float4 v4 = *(const float4*)&ps[row][l*4];
      i32x2 hv;
      hv.x = pk_f16(v4.x, v4.y);
      hv.y = pk_f16(v4.z, v4.w);
      *(i32x2*)(pws + (size_t)row*Sn + g*256 + l*4) = hv;
    }

    // PV for this wave's column slice: B-frag from ps, A-frag = packed V^T
#pragma unroll
    for (int t16 = 0; t16 < 2; ++t16){
      const int c = w*32 + t16*16 + h*8;
      const float2 b0 = *(const float2*)&ps[ln][c];
      const float2 b1 = *(const float2*)&ps[ln][c+2];
      const float2 b2 = *(const float2*)&ps[ln][c+4];
      const float2 b3 = *(const float2*)&ps[ln][c+6];
      int4 bi;
      bi.x = pk_f16(b0.x, b0.y);
      bi.y = pk_f16(b1.x, b1.y);
      bi.z = pk_f16(b2.x, b2.y);
      bi.w = pk_f16(b3.x, b3.y);
      const half8 bf = __builtin_bit_cast(half8, bi);
      const half8* vf = vp + (((size_t)bh*128 + (kt*2 + t16))*4)*64 + l;
#pragma unroll
      for (int dt = 0; dt < 4; ++dt)
        oacc[dt] = __builtin_amdgcn_mfma_f32_32x32x16_f16(vf[(size_t)dt*64], bf, oacc[dt], 0, 0, 0);
    }
    __syncthreads();
  }

  // cross-wave reduce out^T, then coalesced store
#pragma unroll
  for (int dt = 0; dt < 4; ++dt){
#pragma unroll
    for (int r = 0; r < 16; ++r){
      const int d = dt*32 + (r&3) + 8*(r>>2) + h*4;
      atomicAdd(&lds_out[d*33 + ln], oacc[dt][r]);
    }
  }
  __syncthreads();
  const size_t obase = ((size_t)bh*Sn + qb*32)*Dn;
#pragma unroll
  for (int it = 0; it < 2; ++it){
    const int idx = it*512 + tid;
    const int qq  = idx >> 5;
    const int c4  = (idx & 31) * 4;
    f32x4v v4;
    v4.x = lds_out[(c4+0)*33 + qq];
    v4.y = lds_out[(c4+1)*33 + qq];
    v4.z = lds_out[(c4+2)*33 + qq];
    v4.w = lds_out[(c4+3)*33 + qq];
    __builtin_nontemporal_store(v4, (f32x4v*)(out + obase + (size_t)qq*Dn + c4));
  }
}

// ---------------- expansion: single pure grid-stride fp16 -> fp32 copy ----------------
// 4096 strips * 16384 float4-chunks = 67,108,864 chunks; 1,048,576 threads, 64 iters.
// fillBuffer shape: 256-thr blocks, 16B/lane nt stores, no dependent waits.

__global__ __launch_bounds__(256) void k_expand(
    const _Float16* __restrict__ wsp, float* __restrict__ pout)
{
  const int t0 = blockIdx.x*256 + threadIdx.x;      // 0 .. 1048575
#pragma unroll 4
  for (int it = 0; it < 64; ++it){
    const size_t idx   = (size_t)it*1048576 + t0;
    const int    strip = (int)(idx >> 14);          // 16384 chunks per strip
    const int    rem   = (int)(idx & 16383);
    const int    row   = rem >> 9;                  // 512 chunks per 2048-col row
    const int    col4  = (rem & 511) << 2;
    const half4v hv = *(const half4v*)(wsp + (size_t)strip*32*Sn + (size_t)row*Sn + col4);
    f32x4v v4;
    v4.x = (float)hv[0]; v4.y = (float)hv[1];
    v4.z = (float)hv[2]; v4.w = (float)hv[3];
    const size_t dst = (((size_t)(strip >> 6))*Sn + (strip & 63)*32 + row)*Sn + col4;
    __builtin_nontemporal_store(v4, (f32x4v*)(pout + dst));
  }
}

// ---------------- launch ----------------

extern "C" void kernel_launch(void* const* d_in, const int* in_sizes, int n_in,
                              void* d_out, int out_size, void* d_ws, size_t ws_size,
                              hipStream_t stream)
{
  const float* dq = (const float*)d_in[0];
  const float* dk = (const float*)d_in[1];
  const float* dv = (const float*)d_in[2];
  const int*   dm = (const int*)d_in[3];

  char* ws = (char*)d_ws;
  float2*   tab = (float2*)ws;                                   // 1 MiB
  half8*    qp  = (half8*)(ws + (size_t)(1u<<20));               // 32 MiB
  half8*    kp  = (half8*)(ws + (size_t)(1u<<20) + ((size_t)32<<20));
  half8*    vp  = (half8*)(ws + (size_t)(1u<<20) + ((size_t)64<<20));
  unsigned* mtb = (unsigned*)(ws + (size_t)(1u<<20) + ((size_t)96<<20));  // 0.5 MiB
  float2*   mLb = (float2*)(ws + (size_t)(1u<<20) + ((size_t)97<<20));    // 1 MiB
  _Float16* wsp = (_Float16*)(ws + (size_t)(1u<<20) + ((size_t)98<<20));  // 512 MiB

  float* out  = (float*)d_out;
  float* pout = out + (size_t)Bn*Hn*Sn*Dn;

  k_rope_table<<<512,  256, 0, stream>>>(tab);
  k_pack_qk   <<<8192, 256, 0, stream>>>(dq, dk, tab, qp, kp);
  k_pack_v    <<<8192, 256, 0, stream>>>(dv, vp);
  k_maskbits  <<<512,  256, 0, stream>>>(dm, mtb);
  attn_stats  <<<512,  512, 0, stream>>>(qp, kp, mtb, mLb);
  attn_pv     <<<4096, 512, 0, stream>>>(qp, kp, vp, mtb, mLb, out, wsp);
  k_expand    <<<4096, 256, 0, stream>>>(wsp, pout);
}

// Round 11
// 1160.532 us; speedup vs baseline: 1.4129x; 1.4129x over previous
//
#include <hip/hip_runtime.h>
#include <hip/hip_fp16.h>
#include <cstdint>
#include <cstddef>

#define Bn 4
#define Hn 16
#define Sn 2048
#define Dn 128

typedef _Float16 half8  __attribute__((ext_vector_type(8)));
typedef float    f32x16 __attribute__((ext_vector_type(16)));
typedef float    f32x4v __attribute__((ext_vector_type(4)));
typedef unsigned uint4v __attribute__((ext_vector_type(4)));

__device__ __forceinline__ int pk_f16(float a, float b){
  auto h = __builtin_amdgcn_cvt_pkrtz(a, b);   // __fp16x2
  return __builtin_bit_cast(int, h);
}

// ---------------- prep kernels ----------------

__global__ void k_rope_table(float2* __restrict__ tab){
  const int idx = blockIdx.x*256 + threadIdx.x;     // [s][i], 2048*64
  const int i = idx & 63, s = idx >> 6;
  const double invf = exp(-(double)i * (9.210340371976184 / 64.0)); // 10000^(-i/64)
  const double ang  = (double)s * invf;
  float2 cs; cs.x = (float)cos(ang); cs.y = (float)sin(ang);
  tab[idx] = cs;
}

__global__ void k_pack_qk(const float* __restrict__ q, const float* __restrict__ k,
                          const float2* __restrict__ tab,
                          half8* __restrict__ qp, half8* __restrict__ kp){
  const int t    = blockIdx.x*256 + threadIdx.x;    // 2,097,152 chunks
  const int lane = t & 63, ln = lane & 31, h = lane >> 5;
  const int dc   = (t >> 6) & 7;
  const int blk  = (t >> 9) & 63;
  const int bh   = t >> 15;
  const int s    = blk*32 + ln;
  const size_t roff = ((size_t)bh*Sn + s)*Dn + dc*16 + h*8;
  const float4 a0 = *(const float4*)(q + roff);
  const float4 a1 = *(const float4*)(q + roff + 4);
  const float4 b0 = *(const float4*)(k + roff);
  const float4 b1 = *(const float4*)(k + roff + 4);
  const float2* tb = tab + s*64 + dc*8 + h*4;
  const float2 c0 = tb[0], c1 = tb[1], c2 = tb[2], c3 = tb[3];
  const float SC = 0.08838834764831845f;            // 1/sqrt(128) folded into q
  half8 qo, ko;
  qo[0] = (_Float16)((a0.x*c0.x - a0.y*c0.y)*SC);
  qo[1] = (_Float16)((a0.y*c0.x + a0.x*c0.y)*SC);
  qo[2] = (_Float16)((a0.z*c1.x - a0.w*c1.y)*SC);
  qo[3] = (_Float16)((a0.w*c1.x + a0.z*c1.y)*SC);
  qo[4] = (_Float16)((a1.x*c2.x - a1.y*c2.y)*SC);
  qo[5] = (_Float16)((a1.y*c2.x + a1.x*c2.y)*SC);
  qo[6] = (_Float16)((a1.z*c3.x - a1.w*c3.y)*SC);
  qo[7] = (_Float16)((a1.w*c3.x + a1.z*c3.y)*SC);
  ko[0] = (_Float16)(b0.x*c0.x - b0.y*c0.y);
  ko[1] = (_Float16)(b0.y*c0.x + b0.x*c0.y);
  ko[2] = (_Float16)(b0.z*c1.x - b0.w*c1.y);
  ko[3] = (_Float16)(b0.w*c1.x + b0.z*c1.y);
  ko[4] = (_Float16)(b1.x*c2.x - b1.y*c2.y);
  ko[5] = (_Float16)(b1.y*c2.x + b1.x*c2.y);
  ko[6] = (_Float16)(b1.z*c3.x - b1.w*c3.y);
  ko[7] = (_Float16)(b1.w*c3.x + b1.z*c3.y);
  qp[t] = qo;
  kp[t] = ko;
}

__global__ void k_pack_v(const float* __restrict__ v, half8* __restrict__ vp){
  const int t    = blockIdx.x*256 + threadIdx.x;    // 2,097,152 chunks
  const int lane = t & 63, ln = lane & 31, h = lane >> 5;
  const int dt   = (t >> 6) & 3;
  const int k16  = (t >> 8) & 127;
  const int bh   = t >> 15;
  const size_t base = ((size_t)bh*Sn + k16*16 + h*8)*Dn + dt*32 + ln;
  half8 o;
#pragma unroll
  for (int j = 0; j < 8; ++j) o[j] = (_Float16)v[base + (size_t)j*Dn];
  vp[t] = o;
}

__global__ void k_maskbits(const int* __restrict__ mask, unsigned* __restrict__ mtb){
  const int g = blockIdx.x*256 + threadIdx.x;       // [q32][k], 64*2048
  const int k = g & (Sn-1), q32 = g >> 11;
  unsigned bits = 0u;
  for (int j = 0; j < 32; ++j)
    bits |= (mask[(size_t)(q32*32 + j)*Sn + k] != 0 ? 1u : 0u) << j;
  mtb[g] = bits;
}

// ---------------- pass A: per-row softmax stats (m, L) ----------------

__global__ __launch_bounds__(512, 3) void attn_stats(
    const half8* __restrict__ qp, const half8* __restrict__ kp,
    const unsigned* __restrict__ mtb, float2* __restrict__ mL)
{
  const int bid  = blockIdx.x;
  const int work = ((bid & 7) << 6) + (bid >> 3);   // XCD-contiguous bh ranges
  const int bh   = work >> 3;
  const int qg   = work & 7;
  const int w    = threadIdx.x >> 6;
  const int l    = threadIdx.x & 63;
  const int ln   = l & 31;
  const int h    = l >> 5;
  const int qb   = qg*8 + w;

  half8 qf[8];
#pragma unroll
  for (int dc = 0; dc < 8; ++dc)
    qf[dc] = qp[(((size_t)bh*64 + qb)*8 + dc)*64 + l];

  const unsigned* mrow = mtb + (size_t)qb*Sn;
  float m = -3.0e38f, L = 0.f;

  for (int kt = 0; kt < 64; ++kt){
    const half8* kf = kp + (((size_t)bh*64 + kt)*8)*64 + l;
    f32x16 a;
#pragma unroll
    for (int i = 0; i < 16; ++i) a[i] = 0.f;
#pragma unroll
    for (int dc = 0; dc < 8; ++dc)
      a = __builtin_amdgcn_mfma_f32_32x32x16_f16(kf[(size_t)dc*64], qf[dc], a, 0, 0, 0);

    float mt = -3.0e38f;
#pragma unroll
    for (int mm = 0; mm < 4; ++mm){
      const uint4v dw = *(const uint4v*)(mrow + kt*32 + mm*8 + h*4);
#pragma unroll
      for (int aa = 0; aa < 4; ++aa){
        const int r = mm*4 + aa;
        float s = ((dw[aa] >> ln) & 1u) ? a[r] : -1.0e30f;
        a[r] = s;
        mt = fmaxf(mt, s);
      }
    }
    const float mn = fmaxf(m, mt);
    L *= __expf(m - mn);
#pragma unroll
    for (int r = 0; r < 16; ++r) L += __expf(a[r] - mn);
    m = mn;
  }

  const float mo = __shfl_xor(m, 32, 64);
  const float Lo = __shfl_xor(L, 32, 64);
  const float mn = fmaxf(m, mo);
  const float Lc = L*__expf(m - mn) + Lo*__expf(mo - mn);
  if (l < 32){
    float2 st; st.x = mn; st.y = Lc;
    mL[(size_t)bh*Sn + qb*32 + ln] = st;
  }
}

// ---------------- attn_p: QK^T + exp -> p in PV-B-fragment order (fp16) ----------------
// grid 512 = BH*8; block 512 = 8 waves; wave w -> strip qb = qg*8+w (32 q-rows).
// No LDS, no barriers, no V. Per kt: 2 half8 stores (1KB/wave-instr),
// contiguous 128KB per strip ascending in time.

__global__ __launch_bounds__(512, 2) void attn_p(
    const half8* __restrict__ qp, const half8* __restrict__ kp,
    const unsigned* __restrict__ mtb, const float2* __restrict__ mL,
    half8* __restrict__ wfrag)
{
  const int bid  = blockIdx.x;
  const int work = ((bid & 7) << 6) + (bid >> 3);   // XCD-contiguous bh ranges
  const int bh   = work >> 3;
  const int qg   = work & 7;
  const int w    = threadIdx.x >> 6;
  const int l    = threadIdx.x & 63;
  const int ln   = l & 31;
  const int h    = l >> 5;
  const int qb   = qg*8 + w;
  const int strip = bh*64 + qb;

  half8 qf[8];
#pragma unroll
  for (int dc = 0; dc < 8; ++dc)
    qf[dc] = qp[(((size_t)bh*64 + qb)*8 + dc)*64 + l];

  const float2 st = mL[(size_t)bh*Sn + qb*32 + ln];
  const float m    = st.x;
  const float rinv = 1.0f / st.y;

  const unsigned* mrow = mtb + (size_t)qb*Sn;
  half8* wbase = wfrag + (size_t)strip*128*64;

  for (int kt = 0; kt < 64; ++kt){
    // QK^T tile (bitwise-identical MFMA sequence to pass A)
    const half8* kf = kp + (((size_t)bh*64 + kt)*8)*64 + l;
    f32x16 a;
#pragma unroll
    for (int i = 0; i < 16; ++i) a[i] = 0.f;
#pragma unroll
    for (int dc = 0; dc < 8; ++dc)
      a = __builtin_amdgcn_mfma_f32_32x32x16_f16(kf[(size_t)dc*64], qf[dc], a, 0, 0, 0);

    // mask + p = exp(s-m)/L
#pragma unroll
    for (int mm = 0; mm < 4; ++mm){
      const uint4v dw = *(const uint4v*)(mrow + kt*32 + mm*8 + h*4);
#pragma unroll
      for (int aa = 0; aa < 4; ++aa){
        const int r = mm*4 + aa;
        const float s = ((dw[aa] >> ln) & 1u) ? a[r] : -1.0e30f;
        a[r] = __expf(s - m) * rinv;
      }
    }

    // pack fp16 pairs
    int pk2[4][2];
#pragma unroll
    for (int b = 0; b < 4; ++b){
      pk2[b][0] = pk_f16(a[4*b+0], a[4*b+1]);
      pk2[b][1] = pk_f16(a[4*b+2], a[4*b+3]);
    }

    // build PV B-fragments via half-swap (verified R9 pattern) and store
#pragma unroll
    for (int t16 = 0; t16 < 2; ++t16){
      const int P00 = pk2[2*t16+0][0];
      const int P01 = pk2[2*t16+0][1];
      const int P10 = pk2[2*t16+1][0];
      const int P11 = pk2[2*t16+1][1];
      const int S00 = __shfl_xor(P00, 32, 64);
      const int S01 = __shfl_xor(P01, 32, 64);
      const int S10 = __shfl_xor(P10, 32, 64);
      const int S11 = __shfl_xor(P11, 32, 64);
      int4 bi;
      bi.x = h ? S10 : P00;
      bi.y = h ? S11 : P01;
      bi.z = h ? P10 : S00;
      bi.w = h ? P11 : S01;
      wbase[(size_t)(kt*2 + t16)*64 + l] = __builtin_bit_cast(half8, bi);
    }
  }
}

// ---------------- attn_o: pure PV GEMM from p-fragments ----------------
// grid 512 = BH*8; block 512 = 8 waves; wave w -> strip qb = qg*8+w.
// B-frag read back exactly as stored (coalesced); A-frag = packed V^T (L2-hot).

__global__ __launch_bounds__(512, 2) void attn_o(
    const half8* __restrict__ vp, const half8* __restrict__ wfrag,
    float* __restrict__ out)
{
  __shared__ float pt[8][32][34];

  const int bid  = blockIdx.x;
  const int work = ((bid & 7) << 6) + (bid >> 3);
  const int bh   = work >> 3;
  const int qg   = work & 7;
  const int w    = threadIdx.x >> 6;
  const int l    = threadIdx.x & 63;
  const int ln   = l & 31;
  const int h    = l >> 5;
  const int qb   = qg*8 + w;
  const int strip = bh*64 + qb;

  f32x16 oacc[4];
#pragma unroll
  for (int dt = 0; dt < 4; ++dt)
#pragma unroll
    for (int i = 0; i < 16; ++i) oacc[dt][i] = 0.f;

  const half8* wbase = wfrag + (size_t)strip*128*64;
  const half8* vbase = vp + (size_t)bh*128*4*64;

#pragma unroll 4
  for (int ks = 0; ks < 128; ++ks){
    const half8 bf = wbase[(size_t)ks*64 + l];
    const half8* vf = vbase + (size_t)ks*4*64 + l;
#pragma unroll
    for (int dt = 0; dt < 4; ++dt)
      oacc[dt] = __builtin_amdgcn_mfma_f32_32x32x16_f16(vf[(size_t)dt*64], bf, oacc[dt], 0, 0, 0);
  }

  // per-wave LDS transpose epilogue (verified R4 pattern)
  const size_t obase = ((size_t)bh*Sn + qb*32)*Dn;
  const int rq = l >> 3;
  const int rc = (l & 7) * 4;
#pragma unroll
  for (int dt = 0; dt < 4; ++dt){
#pragma unroll
    for (int g = 0; g < 4; ++g){
      const int c = g*8 + h*4;
      float2 e0, e1;
      e0.x = oacc[dt][4*g+0]; e0.y = oacc[dt][4*g+1];
      e1.x = oacc[dt][4*g+2]; e1.y = oacc[dt][4*g+3];
      *(float2*)&pt[w][ln][c]   = e0;
      *(float2*)&pt[w][ln][c+2] = e1;
    }
#pragma unroll
    for (int i = 0; i < 4; ++i){
      const int qq = i*8 + rq;
      const float2 t0 = *(const float2*)&pt[w][qq][rc];
      const float2 t1 = *(const float2*)&pt[w][qq][rc+2];
      f32x4v o4; o4.x = t0.x; o4.y = t0.y; o4.z = t1.x; o4.w = t1.y;
      __builtin_nontemporal_store(o4, (f32x4v*)(out + obase + (size_t)qq*Dn + dt*32 + rc));
    }
  }
}

// ---------------- k_expand: fragment -> row-major fp32 via LDS transpose ----------------
// grid 8192 = 4096 strips x 2 halves; block 512. Reads 64 fragment chunks
// (coalesced 1KB), transposes in LDS, writes 32 rows x 4KB contiguous fp32.

__global__ __launch_bounds__(512, 2) void k_expand(
    const half8* __restrict__ wfrag, float* __restrict__ pout)
{
  __shared__ _Float16 ps[32][1032];   // 66,048 B; row stride 2064 B (16B-aligned)

  const int b     = blockIdx.x;
  const int strip = b >> 1;
  const int hh    = b & 1;
  const int tid   = threadIdx.x;
  const int l     = tid & 63;
  const int w8    = tid >> 6;
  const int ln    = l & 31;
  const int h     = l >> 5;

#pragma unroll
  for (int i = 0; i < 8; ++i){
    const int cc = w8*8 + i;          // 0..63 k16-chunks in this half
    const half8 v = wfrag[((size_t)strip*128 + hh*64 + cc)*64 + l];
    *(half8*)&ps[ln][cc*16 + h*8] = v;   // row ln, cols cc*16+h*8..+7
  }
  __syncthreads();

  const int bh = strip >> 6, qb = strip & 63;
  float* dst0 = pout + ((size_t)bh*Sn + qb*32)*Sn + hh*1024;
#pragma unroll
  for (int it = 0; it < 8; ++it){
    const int id  = it*512 + tid;     // 4096 16B-chunks
    const int row = id >> 7;          // 128 chunks per 1024-col row
    const int c   = (id & 127) * 8;
    const half8 hv = *(const half8*)&ps[row][c];
    f32x4v v0, v1;
    v0.x = (float)hv[0]; v0.y = (float)hv[1]; v0.z = (float)hv[2]; v0.w = (float)hv[3];
    v1.x = (float)hv[4]; v1.y = (float)hv[5]; v1.z = (float)hv[6]; v1.w = (float)hv[7];
    float* dp = dst0 + (size_t)row*Sn + c;
    __builtin_nontemporal_store(v0, (f32x4v*)dp);
    __builtin_nontemporal_store(v1, (f32x4v*)(dp + 4));
  }
}

// ---------------- launch ----------------

extern "C" void kernel_launch(void* const* d_in, const int* in_sizes, int n_in,
                              void* d_out, int out_size, void* d_ws, size_t ws_size,
                              hipStream_t stream)
{
  const float* dq = (const float*)d_in[0];
  const float* dk = (const float*)d_in[1];
  const float* dv = (const float*)d_in[2];
  const int*   dm = (const int*)d_in[3];

  char* ws = (char*)d_ws;
  float2*   tab = (float2*)ws;                                   // 1 MiB
  half8*    qp  = (half8*)(ws + (size_t)(1u<<20));               // 32 MiB
  half8*    kp  = (half8*)(ws + (size_t)(1u<<20) + ((size_t)32<<20));
  half8*    vp  = (half8*)(ws + (size_t)(1u<<20) + ((size_t)64<<20));
  unsigned* mtb = (unsigned*)(ws + (size_t)(1u<<20) + ((size_t)96<<20));  // 0.5 MiB
  float2*   mLb = (float2*)(ws + (size_t)(1u<<20) + ((size_t)97<<20));    // 1 MiB
  half8*    wfr = (half8*)(ws + (size_t)(1u<<20) + ((size_t)98<<20));     // 512 MiB

  float* out  = (float*)d_out;
  float* pout = out + (size_t)Bn*Hn*Sn*Dn;

  k_rope_table<<<512,  256, 0, stream>>>(tab);
  k_pack_qk   <<<8192, 256, 0, stream>>>(dq, dk, tab, qp, kp);
  k_pack_v    <<<8192, 256, 0, stream>>>(dv, vp);
  k_maskbits  <<<512,  256, 0, stream>>>(dm, mtb);
  attn_stats  <<<512,  512, 0, stream>>>(qp, kp, mtb, mLb);
  attn_p      <<<512,  512, 0, stream>>>(qp, kp, mtb, mLb, wfr);
  attn_o      <<<512,  512, 0, stream>>>(vp, wfr, out);
  k_expand    <<<8192, 512, 0, stream>>>(wfr, pout);
}